// Round 1
// baseline (3166.087 us; speedup 1.0000x reference)
//
#include <hip/hip_runtime.h>
#include <math.h>

#define S_LEN 1024
#define BATCH 2048
#define MTILE 8
#define HID   128
#define NBLK  (BATCH / MTILE)   // 256 blocks -> every CU active
#define INV2048 (1.0f / 2048.0f)

// ws layout, offsets in _Float16 elements. Ten [128][128] hi/lo arrays
// (K-extension columns removed from the GEMM; handled in f32 VALU).
#define H_M1H 0
#define H_M1L 16384
#define H_MSH 32768
#define H_MSL 49152
#define H_ASH 65536
#define H_ASL 81920
#define H_WMH 98304      // [128][128] WtauM[:,128:256] hi
#define H_WML 114688
#define H_WBH 131072     // [128][128] WtauAdp[:,128:256] hi
#define H_WBL 147456
#define H_END 163840
// f32 ext-coefficient table: [128 h][12] = (d: b,w0,w1,pad | M: b,s0,s1,pad | A: ...)
#define OFF_EXT_F  81920         // float index (== H_END halfs)
#define OFF_PART_F 83456         // float index of per-block partials [256]

typedef _Float16 half8 __attribute__((ext_vector_type(8)));
typedef _Float16 half4 __attribute__((ext_vector_type(4)));
typedef float floatx4 __attribute__((ext_vector_type(4)));

#define MFMA(a, b, c) __builtin_amdgcn_mfma_f32_16x16x32_f16((a), (b), (c), 0, 0, 0)

__device__ __forceinline__ void put_hl(_Float16* ws, int hiBase, int loBase,
                                       int idx, float v) {
  _Float16 hi = (_Float16)v;
  ws[hiBase + idx] = hi;
  ws[loBase + idx] = (_Float16)((v - (float)hi) * 2048.0f);
}

// DPP row_ror:8 == xor-8 within each 16-lane row (8 is half the ring).
// Replaces ds_swizzle-based __shfl_xor(v,8): VALU pipe instead of LDS pipe.
__device__ __forceinline__ float dpp_xor8(float v) {
  int sw = __builtin_amdgcn_update_dpp(0, __float_as_int(v),
                                       0x128 /*row_ror:8*/, 0xF, 0xF, true);
  return __int_as_float(sw);
}

// ---- prep: fold dense->tau coupling into f16 hi/lo fragment arrays,
// plus f32 ext coefficients (bias + x-coupling) for the VALU path.
__global__ __launch_bounds__(192) void prep(
    const float* __restrict__ W1x, const float* __restrict__ b1x,
    const float* __restrict__ WtauM, const float* __restrict__ btauM,
    const float* __restrict__ WtauAdp, const float* __restrict__ btauAdp,
    _Float16* __restrict__ ws) {
  const int h = blockIdx.x, k = threadIdx.x;
  if (k < 128) {
    float w1 = W1x[h * 130 + 2 + k];
    float s1 = 0.f, s2 = 0.f;
    for (int d = 0; d < 128; ++d) {
      float wd = W1x[d * 130 + 2 + k];
      s1 += WtauM[h * 256 + d] * wd;
      s2 += WtauAdp[h * 256 + d] * wd;
    }
    put_hl(ws, H_M1H, H_M1L, h * 128 + k, w1);
    put_hl(ws, H_MSH, H_MSL, h * 128 + k, s1);
    put_hl(ws, H_ASH, H_ASL, h * 128 + k, s2);
    put_hl(ws, H_WMH, H_WML, h * 128 + k, WtauM[h * 256 + 128 + k]);
    put_hl(ws, H_WBH, H_WBL, h * 128 + k, WtauAdp[h * 256 + 128 + k]);
  } else if (k < 131) {
    const int col = k - 128;   // 0: bias, 1: x0-coef, 2: x1-coef
    float m1v = (col == 0) ? b1x[h] : W1x[h * 130 + (col - 1)];
    float sm = 0.f, sa = 0.f;
    for (int d = 0; d < 128; ++d) {
      float cv = (col == 0) ? b1x[d] : W1x[d * 130 + (col - 1)];
      sm += WtauM[h * 256 + d] * cv;
      sa += WtauAdp[h * 256 + d] * cv;
    }
    if (col == 0) { sm += btauM[h]; sa += btauAdp[h]; }
    float* EXT = (float*)ws + OFF_EXT_F;
    EXT[h * 12 + 0 + col] = m1v;
    EXT[h * 12 + 4 + col] = sm;
    EXT[h * 12 + 8 + col] = sa;
    if (col == 0) {  // zero the pad lanes of the float4 loads
      EXT[h * 12 + 3] = 0.f; EXT[h * 12 + 7] = 0.f; EXT[h * 12 + 11] = 0.f;
    }
  }
}

// State slabs. mem/bbp per k-chunk: 1 KB, half-index (q'*16+n')*8+j holds
// B[k=f*32+q'*8+j][n']; n'=0..7 hi, n'=8..15 lo(x2048). spk has NO lo
// (0/1 exact in f16) -> packed 8 cols, 512 B, read exec-masked by the 32
// active lanes; inactive lanes keep persistent zero fragments.
struct SLds {
  _Float16 spk[2][4][256];
  _Float16 mem[2][4][512];
  _Float16 bbp[2][4][512];
  float red[8][8];
  float red2[8];
};

__global__ __launch_bounds__(512, 2) void snn_main(
    const float* __restrict__ x, const float* __restrict__ y,
    const float* __restrict__ h0m, const float* __restrict__ h0s,
    const float* __restrict__ h0b,
    const float* __restrict__ Wlin, const float* __restrict__ blin,
    const _Float16* __restrict__ W, float* __restrict__ wsout) {
  __shared__ SLds L;

  const int tid  = threadIdx.x;
  const int w    = tid >> 6;      // wave 0..7, owns h-slice [16w, 16w+16)
  const int lane = tid & 63;
  const int c    = lane & 15;     // A-frag m / B-frag n / C col
  const int q    = lane >> 4;
  const int bbase = blockIdx.x * MTILE;
  const bool act = (c < 8);       // cols 8..15 are lo-lanes (no real batch)

  // ---- Register-resident A-frag weights (MFMA-only -> AGPR side)
  half8 m1h[4], m1l[4], msh[4], msl[4], ash[4], asl[4];
  half8 wmh[4], wml[4], wbh[4], wbl[4];
  {
    const int hA = w * 16 + c;
#pragma unroll
    for (int f = 0; f < 4; ++f) {
      const int o = hA * 128 + f * 32 + q * 8;
      m1h[f] = *(const half8*)&W[H_M1H + o];
      m1l[f] = *(const half8*)&W[H_M1L + o];
      msh[f] = *(const half8*)&W[H_MSH + o];
      msl[f] = *(const half8*)&W[H_MSL + o];
      ash[f] = *(const half8*)&W[H_ASH + o];
      asl[f] = *(const half8*)&W[H_ASL + o];
      wmh[f] = *(const half8*)&W[H_WMH + o];
      wml[f] = *(const half8*)&W[H_WML + o];
      wbh[f] = *(const half8*)&W[H_WBH + o];
      wbl[f] = *(const half8*)&W[H_WBL + o];
    }
  }

  // ---- f32 ext coefficients for h = w*16 + q*4 + r  (exact VALU path)
  const float* EXT = (const float*)W + OFF_EXT_F;
  floatx4 eD[4], eM[4], eA[4];
#pragma unroll
  for (int r = 0; r < 4; ++r) {
    const int hb = (w * 16 + q * 4 + r) * 12;
    eD[r] = *(const floatx4*)&EXT[hb + 0];
    eM[r] = *(const floatx4*)&EXT[hb + 4];
    eA[r] = *(const floatx4*)&EXT[hb + 8];
  }

  // ---- Per-lane recurrent state (act lanes): h = w*16 + q*4 + r, b = bbase+c
  float memv[4], spk[4], bb[4];
#pragma unroll
  for (int r = 0; r < 4; ++r) { memv[r] = 0.f; spk[r] = 0.f; bb[r] = 0.f; }
  if (act) {
#pragma unroll
    for (int r = 0; r < 4; ++r) {
      const int gi = (bbase + c) * HID + w * 16 + q * 4 + r;
      memv[r] = h0m[gi]; spk[r] = h0s[gi]; bb[r] = h0b[gi];
    }
  }

  // State value (h = w*16+q*4+r) enters GEMM2 as B[k=h][n]:
  // chunk fW = w>>1, granule qp = (w&1)*2 + (q>>1), j = (q&1)*4 + r.
  const int fW  = w >> 1;
  const int qp  = (w & 1) * 2 + (q >> 1);
  const int wiH = (qp * 16 + c) * 8 + (q & 1) * 4;        // mem/bbp hi
  const int wiL = (qp * 16 + c + 8) * 8 + (q & 1) * 4;    // mem/bbp lo
  const int wiS = (qp * 8 + c) * 8 + (q & 1) * 4;         // spk (8-col slab)
  const int ri  = lane * 8;                                // mem/bbp read
  const int riS = (q * 8 + c) * 8;                         // spk read (act)

  if (act) {   // initial state into buf 0 via the standard write path
    half4 ps, mh4, ml4, bh4, bl4;
#pragma unroll
    for (int r = 0; r < 4; ++r) {
      ps[r] = (_Float16)spk[r];
      float v = memv[r]; _Float16 hi = (_Float16)v;
      mh4[r] = hi; ml4[r] = (_Float16)((v - (float)hi) * 2048.0f);
      v = bb[r]; hi = (_Float16)v;
      bh4[r] = hi; bl4[r] = (_Float16)((v - (float)hi) * 2048.0f);
    }
    *(half4*)&L.spk[0][fW][wiS] = ps;
    *(half4*)&L.mem[0][fW][wiH] = mh4; *(half4*)&L.mem[0][fW][wiL] = ml4;
    *(half4*)&L.bbp[0][fW][wiH] = bh4; *(half4*)&L.bbp[0][fW][wiL] = bl4;
  }
  __syncthreads();

  // Persistent-zero spike fragments: inactive lanes (c>=8) must stay 0 so
  // partner-lane MFMA columns carry pure w_hi*v_lo terms for the folds.
  half8 Sf[4];
  {
    half8 z;
#pragma unroll
    for (int j = 0; j < 8; ++j) z[j] = (_Float16)0;
#pragma unroll
    for (int f = 0; f < 4; ++f) Sf[f] = z;
  }

  // Register-prefetched x for batch bbase + (c&7) (junk lanes mirror c-8)
  const float* xb = x + (size_t)(bbase + (c & 7)) * 2;
  float2 xv = *(const float2*)xb;   // x at t=0

#pragma unroll 1
  for (int t = 0; t < S_LEN; ++t) {
    const int p = t & 1, pn = p ^ 1;
    const size_t tn = (t + 1 < S_LEN) ? (size_t)(t + 1) : (size_t)t;
    float2 xnx = *(const float2*)(xb + tn * (size_t)(BATCH * 2));  // prefetch

    half8 Mv[4], Bv[4];
#pragma unroll
    for (int f = 0; f < 4; ++f) {
      if (act) Sf[f] = *(const half8*)&L.spk[p][f][riS];   // masked 32-lane
      Mv[f] = *(const half8*)&L.mem[p][f][ri];             // [mh | ml]
      Bv[f] = *(const half8*)&L.bbp[p][f][ri];             // [bh | bl]
    }

    floatx4 d1 = {0.f,0.f,0.f,0.f}, d2 = {0.f,0.f,0.f,0.f};
    floatx4 m1 = {0.f,0.f,0.f,0.f}, m2 = {0.f,0.f,0.f,0.f};
    floatx4 a1 = {0.f,0.f,0.f,0.f}, a2 = {0.f,0.f,0.f,0.f};

#pragma unroll
    for (int f = 0; f < 4; ++f) {
      d1 = MFMA(m1h[f], Sf[f], d1);
      d2 = MFMA(m1l[f], Sf[f], d2);
      m1 = MFMA(msh[f], Sf[f], m1);
      m1 = MFMA(wmh[f], Mv[f], m1);    // cols0-7: wmh*mh ; cols8-15: wmh*ml
      m2 = MFMA(msl[f], Sf[f], m2);
      m2 = MFMA(wml[f], Mv[f], m2);    // cols0-7: wml*mh ; cols8-15: junk
      a1 = MFMA(ash[f], Sf[f], a1);
      a1 = MFMA(wbh[f], Bv[f], a1);
      a2 = MFMA(asl[f], Sf[f], a2);
      a2 = MFMA(wbl[f], Bv[f], a2);
    }

    // Fold partner-lane lo-sums via DPP (VALU), not LDS swizzle.
    // d-gate needs no fold: spk cols 8-15 are exactly 0 -> d1[c+8] == 0.
#pragma unroll
    for (int r = 0; r < 4; ++r) {
      m2[r] += dpp_xor8(m1[r]);
      a2[r] += dpp_xor8(a1[r]);
    }

    // ---- Elementwise update (all lanes; junk in c>=8 stays private)
    half4 ps, mh4, ml4, bh4, bl4;
#pragma unroll
    for (int r = 0; r < 4; ++r) {
      float den  = d1[r] + d2[r] * INV2048
                 + (eD[r][0] + eD[r][1] * xv.x + eD[r][2] * xv.y);
      float preM = m1[r] + m2[r] * INV2048
                 + (eM[r][0] + eM[r][1] * xv.x + eM[r][2] * xv.y);
      float preA = a1[r] + a2[r] * INV2048
                 + (eA[r][0] + eA[r][1] * xv.x + eA[r][2] * xv.y);
      float tM = __builtin_amdgcn_rcpf(1.0f + __expf(-preM));
      float tA = __builtin_amdgcn_rcpf(1.0f + __expf(-preA));
      bb[r] = tA * bb[r] + (1.0f - tA) * spk[r];
      float Bth = 0.01f + 1.8f * bb[r];
      memv[r] = memv[r] * tM + (1.0f - tM) * den - Bth * spk[r];
      spk[r] = (memv[r] - Bth) > 0.0f ? 1.0f : 0.0f;
      ps[r] = (_Float16)spk[r];
      float v = memv[r]; _Float16 hi = (_Float16)v;
      mh4[r] = hi; ml4[r] = (_Float16)((v - (float)hi) * 2048.0f);
      v = bb[r]; hi = (_Float16)v;
      bh4[r] = hi; bl4[r] = (_Float16)((v - (float)hi) * 2048.0f);
    }
    if (act) {   // guarded stores only
      *(half4*)&L.spk[pn][fW][wiS] = ps;
      *(half4*)&L.mem[pn][fW][wiH] = mh4; *(half4*)&L.mem[pn][fW][wiL] = ml4;
      *(half4*)&L.bbp[pn][fW][wiH] = bh4; *(half4*)&L.bbp[pn][fW][wiL] = bl4;
    }
    xv = xnx;
    __syncthreads();
  }

  // ---- Readout: out[b] = mem[b,:] @ Wlin + blin; per-block loss partial
  float part = 0.0f;
#pragma unroll
  for (int r = 0; r < 4; ++r)
    part += memv[r] * Wlin[w * 16 + q * 4 + r];
  part += __shfl_xor(part, 16);
  part += __shfl_xor(part, 32);   // sum over q (same c)
  if (lane < 8) L.red[w][c] = part;
  __syncthreads();
  if (tid < 8) {
    float s = 0.0f;
#pragma unroll
    for (int ww = 0; ww < 8; ++ww) s += L.red[ww][tid];
    float out = s + blin[0];
    float d = out - y[bbase + tid];
    L.red2[tid] = d * d;
  }
  __syncthreads();
  if (tid == 0) {
    float s = 0.0f;
#pragma unroll
    for (int m = 0; m < MTILE; ++m) s += L.red2[m];
    wsout[blockIdx.x] = s;
  }
}

__global__ __launch_bounds__(256) void final_reduce(const float* __restrict__ part,
                                                    float* __restrict__ out) {
  __shared__ float sh[256];
  int t = threadIdx.x;
  sh[t] = part[t];
  __syncthreads();
  for (int s = 128; s > 0; s >>= 1) {
    if (t < s) sh[t] += sh[t + s];
    __syncthreads();
  }
  if (t == 0) out[0] = sh[0] * (1.0f / (float)BATCH);
}

extern "C" void kernel_launch(void* const* d_in, const int* in_sizes, int n_in,
                              void* d_out, int out_size, void* d_ws, size_t ws_size,
                              hipStream_t stream) {
  const float* x       = (const float*)d_in[0];
  const float* y       = (const float*)d_in[1];
  const float* h0m     = (const float*)d_in[2];
  const float* h0s     = (const float*)d_in[3];
  const float* h0b     = (const float*)d_in[4];
  const float* W1x     = (const float*)d_in[5];
  const float* b1x     = (const float*)d_in[6];
  const float* WtauM   = (const float*)d_in[7];
  const float* btauM   = (const float*)d_in[8];
  const float* WtauAdp = (const float*)d_in[9];
  const float* btauAdp = (const float*)d_in[10];
  const float* Wlin    = (const float*)d_in[11];
  const float* blin    = (const float*)d_in[12];
  _Float16* wsf16 = (_Float16*)d_ws;
  float* wspart = (float*)d_ws + OFF_PART_F;

  prep<<<128, 192, 0, stream>>>(W1x, b1x, WtauM, btauM, WtauAdp, btauAdp, wsf16);
  snn_main<<<NBLK, 512, 0, stream>>>(x, y, h0m, h0s, h0b, Wlin, blin,
                                     wsf16, wspart);
  final_reduce<<<1, 256, 0, stream>>>(wspart, (float*)d_out);
}

// Round 2
// 2110.623 us; speedup vs baseline: 1.5001x; 1.5001x over previous
//
#include <hip/hip_runtime.h>
#include <math.h>

#define S_LEN 1024
#define BATCH 2048
#define MTILE 8
#define HID   128
#define NBLK  (BATCH / MTILE)   // 256 blocks -> every CU active
#define INV2048 (1.0f / 2048.0f)

// ws layout, offsets in _Float16 elements. K-extended arrays are [128][160]:
// k<128 = real weights, k=128..130 = (bias, x0-coef, x1-coef), k=131..159 = 0.
#define H_M1H 0
#define H_M1L 20480
#define H_MSH 40960
#define H_MSL 61440
#define H_ASH 81920
#define H_ASL 102400
#define H_WMH 122880     // [128][128] WtauM[:,128:256] hi
#define H_WML 139264
#define H_WBH 155648     // [128][128] WtauAdp[:,128:256] hi
#define H_WBL 172032
#define OFF_PART_F 94208 // float index into ws for per-block partials [256]

typedef _Float16 half8 __attribute__((ext_vector_type(8)));
typedef _Float16 half4 __attribute__((ext_vector_type(4)));
typedef float floatx4 __attribute__((ext_vector_type(4)));

#define MFMA(a, b, c) __builtin_amdgcn_mfma_f32_16x16x32_f16((a), (b), (c), 0, 0, 0)

__device__ __forceinline__ void put_hl(_Float16* ws, int hiBase, int loBase,
                                       int idx, float v) {
  _Float16 hi = (_Float16)v;
  ws[hiBase + idx] = hi;
  ws[loBase + idx] = (_Float16)((v - (float)hi) * 2048.0f);
}

// DPP row_ror:8 == xor-8 within each 16-lane row (8 = half the 16-ring).
// Replaces ds_swizzle-based __shfl_xor(v,8): VALU pipe instead of the
// over-subscribed LDS pipe. All 64 lanes are active at the call sites.
__device__ __forceinline__ float dpp_xor8(float v) {
  int sw = __builtin_amdgcn_update_dpp(0, __float_as_int(v),
                                       0x128 /*row_ror:8*/, 0xF, 0xF, true);
  return __int_as_float(sw);
}

// ---- prep: fold dense->tau coupling + all per-h scalars into f16 hi/lo
// fragment-ready arrays. (unchanged)
__global__ __launch_bounds__(192) void prep(
    const float* __restrict__ W1x, const float* __restrict__ b1x,
    const float* __restrict__ WtauM, const float* __restrict__ btauM,
    const float* __restrict__ WtauAdp, const float* __restrict__ btauAdp,
    _Float16* __restrict__ ws) {
  const int h = blockIdx.x, k = threadIdx.x;
  if (k >= 160) return;
  if (k < 128) {
    float w1 = W1x[h * 130 + 2 + k];
    float s1 = 0.f, s2 = 0.f;
    for (int d = 0; d < 128; ++d) {
      float wd = W1x[d * 130 + 2 + k];
      s1 += WtauM[h * 256 + d] * wd;
      s2 += WtauAdp[h * 256 + d] * wd;
    }
    put_hl(ws, H_M1H, H_M1L, h * 160 + k, w1);
    put_hl(ws, H_MSH, H_MSL, h * 160 + k, s1);
    put_hl(ws, H_ASH, H_ASL, h * 160 + k, s2);
    put_hl(ws, H_WMH, H_WML, h * 128 + k, WtauM[h * 256 + 128 + k]);
    put_hl(ws, H_WBH, H_WBL, h * 128 + k, WtauAdp[h * 256 + 128 + k]);
  } else if (k < 131) {
    const int col = k - 128;   // 0: bias, 1: x0-coef, 2: x1-coef
    float m1v = (col == 0) ? b1x[h] : W1x[h * 130 + (col - 1)];
    float sm = 0.f, sa = 0.f;
    for (int d = 0; d < 128; ++d) {
      float cv = (col == 0) ? b1x[d] : W1x[d * 130 + (col - 1)];
      sm += WtauM[h * 256 + d] * cv;
      sa += WtauAdp[h * 256 + d] * cv;
    }
    if (col == 0) { sm += btauM[h]; sa += btauAdp[h]; }
    put_hl(ws, H_M1H, H_M1L, h * 160 + k, m1v);
    put_hl(ws, H_MSH, H_MSL, h * 160 + k, sm);
    put_hl(ws, H_ASH, H_ASL, h * 160 + k, sa);
  } else {
    put_hl(ws, H_M1H, H_M1L, h * 160 + k, 0.f);
    put_hl(ws, H_MSH, H_MSL, h * 160 + k, 0.f);
    put_hl(ws, H_ASH, H_ASL, h * 160 + k, 0.f);
  }
}

// State slabs: per k-chunk f, 1 KB; half-index (q'*16 + n')*8 + j holds
// B[k=f*32+q'*8+j][n']. n'=0..7: batch HI; n'=8..15: batch LO (x2048);
// spk n'>=8 stays zero. Lane (c,q) reads half-index (q*16+c)*8 = lane*8
// -> identity lane-contiguous b128 (m97 fast path, conflict-free).
struct SLds {
  _Float16 spk[2][4][512];
  _Float16 bx[2][512];          // K-ext [1,x0,x1] operand, hi|lo packed
  _Float16 mem[2][4][512];
  _Float16 bbp[2][4][512];
  float red[8][8];
  float red2[8];
};

__global__ __launch_bounds__(512, 2) void snn_main(
    const float* __restrict__ x, const float* __restrict__ y,
    const float* __restrict__ h0m, const float* __restrict__ h0s,
    const float* __restrict__ h0b,
    const float* __restrict__ Wlin, const float* __restrict__ blin,
    const _Float16* __restrict__ W, float* __restrict__ wsout) {
  __shared__ SLds L;

  const int tid  = threadIdx.x;
  const int w    = tid >> 6;      // wave 0..7, owns h-slice [16w, 16w+16)
  const int lane = tid & 63;
  const int c    = lane & 15;     // A-frag m / B-frag n / C col
  const int q    = lane >> 4;
  const int bbase = blockIdx.x * MTILE;
  const bool act = (c < 8);       // cols 8..15 are lo-lanes (no real batch)

  // ---- Register-resident A-frag weights (MFMA-only -> AGPR side)
  half8 m1h[5], m1l[5], msh[5], msl[5], ash[5], asl[5];
  half8 wmh[4], wml[4], wbh[4], wbl[4];
  {
    const int hA = w * 16 + c;
#pragma unroll
    for (int f = 0; f < 5; ++f) {
      const int o = hA * 160 + f * 32 + q * 8;
      m1h[f] = *(const half8*)&W[H_M1H + o];
      m1l[f] = *(const half8*)&W[H_M1L + o];
      msh[f] = *(const half8*)&W[H_MSH + o];
      msl[f] = *(const half8*)&W[H_MSL + o];
      ash[f] = *(const half8*)&W[H_ASH + o];
      asl[f] = *(const half8*)&W[H_ASL + o];
    }
#pragma unroll
    for (int f = 0; f < 4; ++f) {
      const int o = hA * 128 + f * 32 + q * 8;
      wmh[f] = *(const half8*)&W[H_WMH + o];
      wml[f] = *(const half8*)&W[H_WML + o];
      wbh[f] = *(const half8*)&W[H_WBH + o];
      wbl[f] = *(const half8*)&W[H_WBL + o];
    }
  }

  // ---- Zero spk (both bufs; lo halves must stay 0) + bx slabs.
  // spk[2][4][512] (2048 u32) + bx[2][512] (512 u32) are contiguous.
  {
    uint32_t* z = (uint32_t*)&L.spk[0][0][0];
#pragma unroll
    for (int j = 0; j < 5; ++j) z[tid + 512 * j] = 0;
  }

  // ---- Per-lane recurrent state (act lanes): h = w*16 + q*4 + r, b = bbase+c
  float memv[4], spk[4], bb[4];
#pragma unroll
  for (int r = 0; r < 4; ++r) { memv[r] = 0.f; spk[r] = 0.f; bb[r] = 0.f; }
  if (act) {
#pragma unroll
    for (int r = 0; r < 4; ++r) {
      const int gi = (bbase + c) * HID + w * 16 + q * 4 + r;
      memv[r] = h0m[gi]; spk[r] = h0s[gi]; bb[r] = h0b[gi];
    }
  }
  __syncthreads();   // zeros visible before value writes

  // State value (h = w*16+q*4+r) enters GEMM2 as B[k=h][n]:
  // chunk fW = w>>1, granule qp = (w&1)*2 + (q>>1), j = (q&1)*4 + r.
  const int fW  = w >> 1;
  const int qp  = (w & 1) * 2 + (q >> 1);
  const int wiH = (qp * 16 + c) * 8 + (q & 1) * 4;        // hi half (n'=c)
  const int wiL = (qp * 16 + c + 8) * 8 + (q & 1) * 4;    // lo half (n'=c+8)
  const int ri  = lane * 8;                                // identity read

  if (act) {   // initial state into buf 0 via the standard write path
    half4 ps, mh4, ml4, bh4, bl4;
#pragma unroll
    for (int r = 0; r < 4; ++r) {
      ps[r] = (_Float16)spk[r];
      float v = memv[r]; _Float16 hi = (_Float16)v;
      mh4[r] = hi; ml4[r] = (_Float16)((v - (float)hi) * 2048.0f);
      v = bb[r]; hi = (_Float16)v;
      bh4[r] = hi; bl4[r] = (_Float16)((v - (float)hi) * 2048.0f);
    }
    *(half4*)&L.spk[0][fW][wiH] = ps;
    *(half4*)&L.mem[0][fW][wiH] = mh4; *(half4*)&L.mem[0][fW][wiL] = ml4;
    *(half4*)&L.bbp[0][fW][wiH] = bh4; *(half4*)&L.bbp[0][fW][wiL] = bl4;
  }
  if (tid < 16) {  // stage bx[0]: granule q'=0, n'=tid -> half-index tid*8
    float2 x0 = *(const float2*)&x[(size_t)(bbase + (tid & 7)) * 2];
    half8 v;
    if (tid < 8) {
      v = half8{(_Float16)1.0f, (_Float16)x0.x, (_Float16)x0.y, 0, 0, 0, 0, 0};
    } else {
      _Float16 xh0 = (_Float16)x0.x, xh1 = (_Float16)x0.y;
      v = half8{0, (_Float16)((x0.x - (float)xh0) * 2048.0f),
                   (_Float16)((x0.y - (float)xh1) * 2048.0f), 0, 0, 0, 0, 0};
    }
    *(half8*)&L.bx[0][tid * 8] = v;
  }
  __syncthreads();

#pragma unroll 1
  for (int t = 0; t < S_LEN; ++t) {
    const int p = t & 1, pn = p ^ 1;

    floatx4 d1 = {0.f,0.f,0.f,0.f}, d2 = {0.f,0.f,0.f,0.f};
    floatx4 m1 = {0.f,0.f,0.f,0.f}, m2 = {0.f,0.f,0.f,0.f};
    floatx4 a1 = {0.f,0.f,0.f,0.f}, a2 = {0.f,0.f,0.f,0.f};

#pragma unroll
    for (int f = 0; f < 4; ++f) {
      half8 S = *(const half8*)&L.spk[p][f][ri];   // [spk | 0]
      half8 M = *(const half8*)&L.mem[p][f][ri];   // [mh  | ml]
      half8 B = *(const half8*)&L.bbp[p][f][ri];   // [bh  | bl]
      d1 = MFMA(m1h[f], S, d1);
      d2 = MFMA(m1l[f], S, d2);
      m1 = MFMA(msh[f], S, m1);
      m1 = MFMA(wmh[f], M, m1);    // cols0-7: wmh*mh ; cols8-15: wmh*ml
      m2 = MFMA(msl[f], S, m2);
      m2 = MFMA(wml[f], M, m2);    // cols0-7: wml*mh ; cols8-15: junk
      a1 = MFMA(ash[f], S, a1);
      a1 = MFMA(wbh[f], B, a1);
      a2 = MFMA(asl[f], S, a2);
      a2 = MFMA(wbl[f], B, a2);
    }
    {  // K-extension: bias + x coupling, hi|lo packed operand
      half8 E = *(const half8*)&L.bx[p][ri];
      d1 = MFMA(m1h[4], E, d1);
      d2 = MFMA(m1l[4], E, d2);
      m1 = MFMA(msh[4], E, m1);
      m2 = MFMA(msl[4], E, m2);
      a1 = MFMA(ash[4], E, a1);
      a2 = MFMA(asl[4], E, a2);
    }

    // Fold partner-lane lo-sums straight into the lo accumulators.
    // DPP (VALU pipe) instead of ds_swizzle (LDS pipe): xor-8 == row_ror:8.
#pragma unroll
    for (int r = 0; r < 4; ++r) {
      d2[r] += dpp_xor8(d1[r]);
      m2[r] += dpp_xor8(m1[r]);
      a2[r] += dpp_xor8(a1[r]);
    }

    // ---- Elementwise update (all lanes; junk in c>=8 stays private)
    half4 ps, mh4, ml4, bh4, bl4;
#pragma unroll
    for (int r = 0; r < 4; ++r) {
      float den  = d1[r] + d2[r] * INV2048;
      float preM = m1[r] + m2[r] * INV2048;
      float preA = a1[r] + a2[r] * INV2048;
      float tM = __builtin_amdgcn_rcpf(1.0f + __expf(-preM));
      float tA = __builtin_amdgcn_rcpf(1.0f + __expf(-preA));
      bb[r] = tA * bb[r] + (1.0f - tA) * spk[r];
      float Bth = 0.01f + 1.8f * bb[r];
      memv[r] = memv[r] * tM + (1.0f - tM) * den - Bth * spk[r];
      spk[r] = (memv[r] - Bth) > 0.0f ? 1.0f : 0.0f;
      ps[r] = (_Float16)spk[r];
      float v = memv[r]; _Float16 hi = (_Float16)v;
      mh4[r] = hi; ml4[r] = (_Float16)((v - (float)hi) * 2048.0f);
      v = bb[r]; hi = (_Float16)v;
      bh4[r] = hi; bl4[r] = (_Float16)((v - (float)hi) * 2048.0f);
    }
    if (act) {   // guarded stores only
      *(half4*)&L.spk[pn][fW][wiH] = ps;
      *(half4*)&L.mem[pn][fW][wiH] = mh4; *(half4*)&L.mem[pn][fW][wiL] = ml4;
      *(half4*)&L.bbp[pn][fW][wiH] = bh4; *(half4*)&L.bbp[pn][fW][wiL] = bl4;
    }

    if (tid < 16) {   // stage next step's K-extension fragment
      const size_t tn = (t + 1 < S_LEN) ? (size_t)(t + 1) : (size_t)t;
      float2 xn = *(const float2*)&x[(tn * BATCH + bbase + (tid & 7)) * 2];
      half8 v;
      if (tid < 8) {
        v = half8{(_Float16)1.0f, (_Float16)xn.x, (_Float16)xn.y, 0, 0, 0, 0, 0};
      } else {
        _Float16 xh0 = (_Float16)xn.x, xh1 = (_Float16)xn.y;
        v = half8{0, (_Float16)((xn.x - (float)xh0) * 2048.0f),
                     (_Float16)((xn.y - (float)xh1) * 2048.0f), 0, 0, 0, 0, 0};
      }
      *(half8*)&L.bx[pn][tid * 8] = v;
    }
    __syncthreads();
  }

  // ---- Readout: out[b] = mem[b,:] @ Wlin + blin; per-block loss partial
  float part = 0.0f;
#pragma unroll
  for (int r = 0; r < 4; ++r)
    part += memv[r] * Wlin[w * 16 + q * 4 + r];
  part += __shfl_xor(part, 16);
  part += __shfl_xor(part, 32);   // sum over q (same c)
  if (lane < 8) L.red[w][c] = part;
  __syncthreads();
  if (tid < 8) {
    float s = 0.0f;
#pragma unroll
    for (int ww = 0; ww < 8; ++ww) s += L.red[ww][tid];
    float out = s + blin[0];
    float d = out - y[bbase + tid];
    L.red2[tid] = d * d;
  }
  __syncthreads();
  if (tid == 0) {
    float s = 0.0f;
#pragma unroll
    for (int m = 0; m < MTILE; ++m) s += L.red2[m];
    wsout[blockIdx.x] = s;
  }
}

__global__ __launch_bounds__(256) void final_reduce(const float* __restrict__ part,
                                                    float* __restrict__ out) {
  __shared__ float sh[256];
  int t = threadIdx.x;
  sh[t] = part[t];
  __syncthreads();
  for (int s = 128; s > 0; s >>= 1) {
    if (t < s) sh[t] += sh[t + s];
    __syncthreads();
  }
  if (t == 0) out[0] = sh[0] * (1.0f / (float)BATCH);
}

extern "C" void kernel_launch(void* const* d_in, const int* in_sizes, int n_in,
                              void* d_out, int out_size, void* d_ws, size_t ws_size,
                              hipStream_t stream) {
  const float* x       = (const float*)d_in[0];
  const float* y       = (const float*)d_in[1];
  const float* h0m     = (const float*)d_in[2];
  const float* h0s     = (const float*)d_in[3];
  const float* h0b     = (const float*)d_in[4];
  const float* W1x     = (const float*)d_in[5];
  const float* b1x     = (const float*)d_in[6];
  const float* WtauM   = (const float*)d_in[7];
  const float* btauM   = (const float*)d_in[8];
  const float* WtauAdp = (const float*)d_in[9];
  const float* btauAdp = (const float*)d_in[10];
  const float* Wlin    = (const float*)d_in[11];
  const float* blin    = (const float*)d_in[12];
  _Float16* wsf16 = (_Float16*)d_ws;
  float* wspart = (float*)d_ws + OFF_PART_F;

  prep<<<128, 192, 0, stream>>>(W1x, b1x, WtauM, btauM, WtauAdp, btauAdp, wsf16);
  snn_main<<<NBLK, 512, 0, stream>>>(x, y, h0m, h0s, h0b, Wlin, blin,
                                     wsf16, wspart);
  final_reduce<<<1, 256, 0, stream>>>(wspart, (float*)d_out);
}

// Round 3
// 1756.842 us; speedup vs baseline: 1.8021x; 1.2014x over previous
//
#include <hip/hip_runtime.h>
#include <math.h>

#define S_LEN 1024
#define BATCH 2048
#define MTILE 8
#define HID   128
#define NBLK  (BATCH / MTILE)   // 256 blocks -> every CU active
#define INV2048 (1.0f / 2048.0f)

// ws layout, offsets in _Float16 elements. K-extended arrays are [128][160]:
// k<128 = real weights, k=128..130 = (bias, x0-coef, x1-coef), k=131..159 = 0.
#define H_M1H 0
#define H_M1L 20480
#define H_MSH 40960
#define H_MSL 61440
#define H_ASH 81920
#define H_ASL 102400
#define H_WMH 122880     // [128][128] WtauM[:,128:256] hi
#define H_WML 139264
#define H_WBH 155648     // [128][128] WtauAdp[:,128:256] hi
#define H_WBL 172032
#define OFF_PART_F 94208 // float index into ws for per-block partials [256]

typedef _Float16 half8 __attribute__((ext_vector_type(8)));
typedef _Float16 half4 __attribute__((ext_vector_type(4)));
typedef float floatx4 __attribute__((ext_vector_type(4)));

#define MFMA(a, b, c) __builtin_amdgcn_mfma_f32_16x16x32_f16((a), (b), (c), 0, 0, 0)

__device__ __forceinline__ void put_hl(_Float16* ws, int hiBase, int loBase,
                                       int idx, float v) {
  _Float16 hi = (_Float16)v;
  ws[hiBase + idx] = hi;
  ws[loBase + idx] = (_Float16)((v - (float)hi) * 2048.0f);
}

// DPP row_ror:8 == xor-8 within each 16-lane row (8 = half the 16-ring).
// VALU pipe instead of the over-subscribed LDS pipe.
__device__ __forceinline__ float dpp_xor8(float v) {
  int sw = __builtin_amdgcn_update_dpp(0, __float_as_int(v),
                                       0x128 /*row_ror:8*/, 0xF, 0xF, true);
  return __int_as_float(sw);
}

// ---- prep: fold dense->tau coupling + all per-h scalars into f16 hi/lo
// fragment-ready arrays. (unchanged)
__global__ __launch_bounds__(192) void prep(
    const float* __restrict__ W1x, const float* __restrict__ b1x,
    const float* __restrict__ WtauM, const float* __restrict__ btauM,
    const float* __restrict__ WtauAdp, const float* __restrict__ btauAdp,
    _Float16* __restrict__ ws) {
  const int h = blockIdx.x, k = threadIdx.x;
  if (k >= 160) return;
  if (k < 128) {
    float w1 = W1x[h * 130 + 2 + k];
    float s1 = 0.f, s2 = 0.f;
    for (int d = 0; d < 128; ++d) {
      float wd = W1x[d * 130 + 2 + k];
      s1 += WtauM[h * 256 + d] * wd;
      s2 += WtauAdp[h * 256 + d] * wd;
    }
    put_hl(ws, H_M1H, H_M1L, h * 160 + k, w1);
    put_hl(ws, H_MSH, H_MSL, h * 160 + k, s1);
    put_hl(ws, H_ASH, H_ASL, h * 160 + k, s2);
    put_hl(ws, H_WMH, H_WML, h * 128 + k, WtauM[h * 256 + 128 + k]);
    put_hl(ws, H_WBH, H_WBL, h * 128 + k, WtauAdp[h * 256 + 128 + k]);
  } else if (k < 131) {
    const int col = k - 128;   // 0: bias, 1: x0-coef, 2: x1-coef
    float m1v = (col == 0) ? b1x[h] : W1x[h * 130 + (col - 1)];
    float sm = 0.f, sa = 0.f;
    for (int d = 0; d < 128; ++d) {
      float cv = (col == 0) ? b1x[d] : W1x[d * 130 + (col - 1)];
      sm += WtauM[h * 256 + d] * cv;
      sa += WtauAdp[h * 256 + d] * cv;
    }
    if (col == 0) { sm += btauM[h]; sa += btauAdp[h]; }
    put_hl(ws, H_M1H, H_M1L, h * 160 + k, m1v);
    put_hl(ws, H_MSH, H_MSL, h * 160 + k, sm);
    put_hl(ws, H_ASH, H_ASL, h * 160 + k, sa);
  } else {
    put_hl(ws, H_M1H, H_M1L, h * 160 + k, 0.f);
    put_hl(ws, H_MSH, H_MSL, h * 160 + k, 0.f);
    put_hl(ws, H_ASH, H_ASL, h * 160 + k, 0.f);
  }
}

// State slabs. mem/bbp per k-chunk: 1 KB, half-index (q'*16+n')*8+j holds
// B[k=f*32+q'*8+j][n']; n'=0..7 hi, n'=8..15 lo(x2048). spk is PACKED to the
// 8 real cols (spike is exact in f16, no lo) -> 512 B/chunk, fully
// overwritten every step (no zero-init). Inactive lanes (c>=8) broadcast-
// read the zero16 block so their S-operand is exactly 0.
struct SLds {
  _Float16 spk[2][4][256];
  _Float16 zero16[8];           // 16 B of zeros, same-address broadcast read
  _Float16 mem[2][4][512];
  _Float16 bbp[2][4][512];
  float red[8][8];
  float red2[8];
};

__global__ __launch_bounds__(512, 2) void snn_main(
    const float* __restrict__ x, const float* __restrict__ y,
    const float* __restrict__ h0m, const float* __restrict__ h0s,
    const float* __restrict__ h0b,
    const float* __restrict__ Wlin, const float* __restrict__ blin,
    const _Float16* __restrict__ W, float* __restrict__ wsout) {
  __shared__ SLds L;

  const int tid  = threadIdx.x;
  const int w    = tid >> 6;      // wave 0..7, owns h-slice [16w, 16w+16)
  const int lane = tid & 63;
  const int c    = lane & 15;     // A-frag m / B-frag n / C col
  const int q    = lane >> 4;
  const int bbase = blockIdx.x * MTILE;
  const bool act = (c < 8);       // cols 8..15 are lo-lanes (no real batch)

  // ---- Register-resident A-frag weights (MFMA-only -> AGPR side)
  half8 m1h[5], m1l[5], msh[5], msl[5], ash[5], asl[5];
  half8 wmh[4], wml[4], wbh[4], wbl[4];
  {
    const int hA = w * 16 + c;
#pragma unroll
    for (int f = 0; f < 5; ++f) {
      const int o = hA * 160 + f * 32 + q * 8;
      m1h[f] = *(const half8*)&W[H_M1H + o];
      m1l[f] = *(const half8*)&W[H_M1L + o];
      msh[f] = *(const half8*)&W[H_MSH + o];
      msl[f] = *(const half8*)&W[H_MSL + o];
      ash[f] = *(const half8*)&W[H_ASH + o];
      asl[f] = *(const half8*)&W[H_ASL + o];
    }
#pragma unroll
    for (int f = 0; f < 4; ++f) {
      const int o = hA * 128 + f * 32 + q * 8;
      wmh[f] = *(const half8*)&W[H_WMH + o];
      wml[f] = *(const half8*)&W[H_WML + o];
      wbh[f] = *(const half8*)&W[H_WBH + o];
      wbl[f] = *(const half8*)&W[H_WBL + o];
    }
  }

  if (tid == 0) {   // 16 B zero block for inactive-lane broadcast reads
    *(half8*)&L.zero16[0] = half8{0, 0, 0, 0, 0, 0, 0, 0};
  }

  // ---- Per-lane recurrent state (act lanes): h = w*16 + q*4 + r, b = bbase+c
  float memv[4], spk[4], bb[4];
#pragma unroll
  for (int r = 0; r < 4; ++r) { memv[r] = 0.f; spk[r] = 0.f; bb[r] = 0.f; }
  if (act) {
#pragma unroll
    for (int r = 0; r < 4; ++r) {
      const int gi = (bbase + c) * HID + w * 16 + q * 4 + r;
      memv[r] = h0m[gi]; spk[r] = h0s[gi]; bb[r] = h0b[gi];
    }
  }

  // State value (h = w*16+q*4+r) enters GEMM2 as B[k=h][n]:
  // chunk fW = w>>1, granule qp = (w&1)*2 + (q>>1), j = (q&1)*4 + r.
  const int fW  = w >> 1;
  const int qp  = (w & 1) * 2 + (q >> 1);
  const int wiH = (qp * 16 + c) * 8 + (q & 1) * 4;        // mem/bbp hi
  const int wiL = wiH + 64;                                // mem/bbp lo
  const int wiS = (qp * 8 + c) * 8 + (q & 1) * 4;         // packed spk
  const int ri  = lane * 8;                                // mem/bbp read
  // spk read: active lanes read their 16 B; inactive broadcast zero16.
  const _Float16* spkB0 = act ? &L.spk[0][0][(q * 8 + c) * 8] : L.zero16;
  const _Float16* spkB1 = act ? &L.spk[1][0][(q * 8 + c) * 8] : L.zero16;
  const int spkStep = act ? 256 : 0;

  if (act) {   // initial state into buf 0 via the standard write path
    half4 ps, mh4, ml4, bh4, bl4;
#pragma unroll
    for (int r = 0; r < 4; ++r) {
      ps[r] = (_Float16)spk[r];
      float v = memv[r]; _Float16 hi = (_Float16)v;
      mh4[r] = hi; ml4[r] = (_Float16)((v - (float)hi) * 2048.0f);
      v = bb[r]; hi = (_Float16)v;
      bh4[r] = hi; bl4[r] = (_Float16)((v - (float)hi) * 2048.0f);
    }
    *(half4*)&L.spk[0][fW][wiS] = ps;
    *(half4*)&L.mem[0][fW][wiH] = mh4; *(half4*)&L.mem[0][fW][wiL] = ml4;
    *(half4*)&L.bbp[0][fW][wiH] = bh4; *(half4*)&L.bbp[0][fW][wiL] = bl4;
  }
  __syncthreads();

  // Per-lane x stream for batch bbase + (c&7), prefetched one step ahead.
  // The K-extension operand E is built in registers each step: hi lanes get
  // {1, x0h, x1h}, lo lanes {0, x0lo, x1lo}; rows k>=131 have zero weights.
  const float* xb = x + (size_t)(bbase + (c & 7)) * 2;
  float2 xv = *(const float2*)xb;   // x at t=0
  const _Float16 e0c = act ? (_Float16)1.0f : (_Float16)0.0f;

#pragma unroll 1
  for (int t = 0; t < S_LEN; ++t) {
    const int p = t & 1, pn = p ^ 1;
    const size_t tn = (t + 1 < S_LEN) ? (size_t)(t + 1) : (size_t)t;
    float2 xnx = *(const float2*)(xb + tn * (size_t)(BATCH * 2));  // prefetch

    // Build E from registers (no LDS): granule-0 rows carry {1|0, x0, x1}.
    // For q>0 lanes the matching weight rows are zero, so E just multiplies
    // by 0 -- values are finite, contribution exact 0.
    half8 E;
    {
      _Float16 xh0 = (_Float16)xv.x, xh1 = (_Float16)xv.y;
      _Float16 xl0 = (_Float16)((xv.x - (float)xh0) * 2048.0f);
      _Float16 xl1 = (_Float16)((xv.y - (float)xh1) * 2048.0f);
      E = half8{e0c, act ? xh0 : xl0, act ? xh1 : xl1, 0, 0, 0, 0, 0};
    }

    const _Float16* sB = p ? spkB1 : spkB0;

    floatx4 d1 = {0.f,0.f,0.f,0.f}, d2 = {0.f,0.f,0.f,0.f};
    floatx4 m1 = {0.f,0.f,0.f,0.f}, m2 = {0.f,0.f,0.f,0.f};
    floatx4 a1 = {0.f,0.f,0.f,0.f}, a2 = {0.f,0.f,0.f,0.f};

#pragma unroll
    for (int f = 0; f < 4; ++f) {
      half8 S = *(const half8*)&sB[f * spkStep];   // [spk] (0 for c>=8)
      half8 M = *(const half8*)&L.mem[p][f][ri];   // [mh  | ml]
      half8 B = *(const half8*)&L.bbp[p][f][ri];   // [bh  | bl]
      d1 = MFMA(m1h[f], S, d1);
      d2 = MFMA(m1l[f], S, d2);
      m1 = MFMA(msh[f], S, m1);
      m1 = MFMA(wmh[f], M, m1);    // cols0-7: wmh*mh ; cols8-15: wmh*ml
      m2 = MFMA(msl[f], S, m2);
      m2 = MFMA(wml[f], M, m2);    // cols0-7: wml*mh ; cols8-15: junk
      a1 = MFMA(ash[f], S, a1);
      a1 = MFMA(wbh[f], B, a1);
      a2 = MFMA(asl[f], S, a2);
      a2 = MFMA(wbl[f], B, a2);
    }
    {  // K-extension: bias + x coupling, register-built operand
      d1 = MFMA(m1h[4], E, d1);
      d2 = MFMA(m1l[4], E, d2);
      m1 = MFMA(msh[4], E, m1);
      m2 = MFMA(msl[4], E, m2);
      a1 = MFMA(ash[4], E, a1);
      a2 = MFMA(asl[4], E, a2);
    }

    // Fold partner-lane lo-sums straight into the lo accumulators (DPP).
#pragma unroll
    for (int r = 0; r < 4; ++r) {
      d2[r] += dpp_xor8(d1[r]);
      m2[r] += dpp_xor8(m1[r]);
      a2[r] += dpp_xor8(a1[r]);
    }

    // ---- Elementwise update (all lanes; junk in c>=8 stays private)
    half4 ps, mh4, ml4, bh4, bl4;
#pragma unroll
    for (int r = 0; r < 4; ++r) {
      float den  = d1[r] + d2[r] * INV2048;
      float preM = m1[r] + m2[r] * INV2048;
      float preA = a1[r] + a2[r] * INV2048;
      float tM = __builtin_amdgcn_rcpf(1.0f + __expf(-preM));
      float tA = __builtin_amdgcn_rcpf(1.0f + __expf(-preA));
      bb[r] = tA * bb[r] + (1.0f - tA) * spk[r];
      float Bth = 0.01f + 1.8f * bb[r];
      memv[r] = memv[r] * tM + (1.0f - tM) * den - Bth * spk[r];
      spk[r] = (memv[r] - Bth) > 0.0f ? 1.0f : 0.0f;
      ps[r] = (_Float16)spk[r];
      float v = memv[r]; _Float16 hi = (_Float16)v;
      mh4[r] = hi; ml4[r] = (_Float16)((v - (float)hi) * 2048.0f);
      v = bb[r]; hi = (_Float16)v;
      bh4[r] = hi; bl4[r] = (_Float16)((v - (float)hi) * 2048.0f);
    }
    if (act) {   // guarded stores only
      *(half4*)&L.spk[pn][fW][wiS] = ps;
      *(half4*)&L.mem[pn][fW][wiH] = mh4; *(half4*)&L.mem[pn][fW][wiL] = ml4;
      *(half4*)&L.bbp[pn][fW][wiH] = bh4; *(half4*)&L.bbp[pn][fW][wiL] = bl4;
    }
    xv = xnx;
    __syncthreads();
  }

  // ---- Readout: out[b] = mem[b,:] @ Wlin + blin; per-block loss partial
  float part = 0.0f;
#pragma unroll
  for (int r = 0; r < 4; ++r)
    part += memv[r] * Wlin[w * 16 + q * 4 + r];
  part += __shfl_xor(part, 16);
  part += __shfl_xor(part, 32);   // sum over q (same c)
  if (lane < 8) L.red[w][c] = part;
  __syncthreads();
  if (tid < 8) {
    float s = 0.0f;
#pragma unroll
    for (int ww = 0; ww < 8; ++ww) s += L.red[ww][tid];
    float out = s + blin[0];
    float d = out - y[bbase + tid];
    L.red2[tid] = d * d;
  }
  __syncthreads();
  if (tid == 0) {
    float s = 0.0f;
#pragma unroll
    for (int m = 0; m < MTILE; ++m) s += L.red2[m];
    wsout[blockIdx.x] = s;
  }
}

__global__ __launch_bounds__(256) void final_reduce(const float* __restrict__ part,
                                                    float* __restrict__ out) {
  __shared__ float sh[256];
  int t = threadIdx.x;
  sh[t] = part[t];
  __syncthreads();
  for (int s = 128; s > 0; s >>= 1) {
    if (t < s) sh[t] += sh[t + s];
    __syncthreads();
  }
  if (t == 0) out[0] = sh[0] * (1.0f / (float)BATCH);
}

extern "C" void kernel_launch(void* const* d_in, const int* in_sizes, int n_in,
                              void* d_out, int out_size, void* d_ws, size_t ws_size,
                              hipStream_t stream) {
  const float* x       = (const float*)d_in[0];
  const float* y       = (const float*)d_in[1];
  const float* h0m     = (const float*)d_in[2];
  const float* h0s     = (const float*)d_in[3];
  const float* h0b     = (const float*)d_in[4];
  const float* W1x     = (const float*)d_in[5];
  const float* b1x     = (const float*)d_in[6];
  const float* WtauM   = (const float*)d_in[7];
  const float* btauM   = (const float*)d_in[8];
  const float* WtauAdp = (const float*)d_in[9];
  const float* btauAdp = (const float*)d_in[10];
  const float* Wlin    = (const float*)d_in[11];
  const float* blin    = (const float*)d_in[12];
  _Float16* wsf16 = (_Float16*)d_ws;
  float* wspart = (float*)d_ws + OFF_PART_F;

  prep<<<128, 192, 0, stream>>>(W1x, b1x, WtauM, btauM, WtauAdp, btauAdp, wsf16);
  snn_main<<<NBLK, 512, 0, stream>>>(x, y, h0m, h0s, h0b, Wlin, blin,
                                     wsf16, wspart);
  final_reduce<<<1, 256, 0, stream>>>(wspart, (float*)d_out);
}

// Round 4
// 1700.724 us; speedup vs baseline: 1.8616x; 1.0330x over previous
//
#include <hip/hip_runtime.h>
#include <math.h>

#define S_LEN 1024
#define BATCH 2048
#define MTILE 8
#define HID   128
#define NBLK  (BATCH / MTILE)   // 256 blocks -> every CU active
#define INV2048 (1.0f / 2048.0f)

// ws layout, offsets in _Float16 elements. K-extended arrays are [128][160]:
// k<128 = real weights, k=128..130 = (bias, x0-coef, x1-coef), k=131..159 = 0.
#define H_M1H 0
#define H_M1L 20480
#define H_MSH 40960
#define H_MSL 61440
#define H_ASH 81920
#define H_ASL 102400
#define H_WMH 122880     // [128][128] WtauM[:,128:256] hi
#define H_WML 139264
#define H_WBH 155648     // [128][128] WtauAdp[:,128:256] hi
#define H_WBL 172032
#define OFF_PART_F 94208 // float index into ws for per-block partials [256]

typedef _Float16 half8 __attribute__((ext_vector_type(8)));
typedef _Float16 half4 __attribute__((ext_vector_type(4)));
typedef _Float16 half2h __attribute__((ext_vector_type(2)));
typedef float floatx4 __attribute__((ext_vector_type(4)));

#define MFMA(a, b, c) __builtin_amdgcn_mfma_f32_16x16x32_f16((a), (b), (c), 0, 0, 0)

__device__ __forceinline__ void put_hl(_Float16* ws, int hiBase, int loBase,
                                       int idx, float v) {
  _Float16 hi = (_Float16)v;
  ws[hiBase + idx] = hi;
  ws[loBase + idx] = (_Float16)((v - (float)hi) * 2048.0f);
}

// DPP row_ror:8 == xor-8 within each 16-lane row (8 = half the 16-ring).
// VALU pipe instead of the over-subscribed LDS pipe.
__device__ __forceinline__ float dpp_xor8(float v) {
  int sw = __builtin_amdgcn_update_dpp(0, __float_as_int(v),
                                       0x128 /*row_ror:8*/, 0xF, 0xF, true);
  return __int_as_float(sw);
}

// Per-gate fold + work split across the c / c+8 lane pair.
// Inputs per r: hi_r (=g1 on side0 lane), lo_r (=g2 on side0 lane),
// cross_r (=g1 on side1 lane). Lane c owns r=0,1; lane c+8 owns r=2,3.
// out[rr] = hi + (lo + cross)*inv -- exact association of the old code.
__device__ __forceinline__ void fold_pair(floatx4 g1, floatx4 g2, bool side,
                                          float out[2]) {
  float c0 = dpp_xor8(g1[0]);   // side0 receives cross_0
  float c1 = dpp_xor8(g1[1]);
  float h2 = dpp_xor8(g1[2]);   // side1 receives hi_2
  float h3 = dpp_xor8(g1[3]);
  float l2 = dpp_xor8(g2[2]);   // side1 receives lo_2
  float l3 = dpp_xor8(g2[3]);
  float hi0 = side ? h2 : g1[0], lo0 = side ? l2 : g2[0];
  float cr0 = side ? g1[2] : c0;
  float hi1 = side ? h3 : g1[1], lo1 = side ? l3 : g2[1];
  float cr1 = side ? g1[3] : c1;
  out[0] = hi0 + (lo0 + cr0) * INV2048;
  out[1] = hi1 + (lo1 + cr1) * INV2048;
}

// ---- prep: fold dense->tau coupling + all per-h scalars into f16 hi/lo
// fragment-ready arrays. (unchanged)
__global__ __launch_bounds__(192) void prep(
    const float* __restrict__ W1x, const float* __restrict__ b1x,
    const float* __restrict__ WtauM, const float* __restrict__ btauM,
    const float* __restrict__ WtauAdp, const float* __restrict__ btauAdp,
    _Float16* __restrict__ ws) {
  const int h = blockIdx.x, k = threadIdx.x;
  if (k >= 160) return;
  if (k < 128) {
    float w1 = W1x[h * 130 + 2 + k];
    float s1 = 0.f, s2 = 0.f;
    for (int d = 0; d < 128; ++d) {
      float wd = W1x[d * 130 + 2 + k];
      s1 += WtauM[h * 256 + d] * wd;
      s2 += WtauAdp[h * 256 + d] * wd;
    }
    put_hl(ws, H_M1H, H_M1L, h * 160 + k, w1);
    put_hl(ws, H_MSH, H_MSL, h * 160 + k, s1);
    put_hl(ws, H_ASH, H_ASL, h * 160 + k, s2);
    put_hl(ws, H_WMH, H_WML, h * 128 + k, WtauM[h * 256 + 128 + k]);
    put_hl(ws, H_WBH, H_WBL, h * 128 + k, WtauAdp[h * 256 + 128 + k]);
  } else if (k < 131) {
    const int col = k - 128;   // 0: bias, 1: x0-coef, 2: x1-coef
    float m1v = (col == 0) ? b1x[h] : W1x[h * 130 + (col - 1)];
    float sm = 0.f, sa = 0.f;
    for (int d = 0; d < 128; ++d) {
      float cv = (col == 0) ? b1x[d] : W1x[d * 130 + (col - 1)];
      sm += WtauM[h * 256 + d] * cv;
      sa += WtauAdp[h * 256 + d] * cv;
    }
    if (col == 0) { sm += btauM[h]; sa += btauAdp[h]; }
    put_hl(ws, H_M1H, H_M1L, h * 160 + k, m1v);
    put_hl(ws, H_MSH, H_MSL, h * 160 + k, sm);
    put_hl(ws, H_ASH, H_ASL, h * 160 + k, sa);
  } else {
    put_hl(ws, H_M1H, H_M1L, h * 160 + k, 0.f);
    put_hl(ws, H_MSH, H_MSL, h * 160 + k, 0.f);
    put_hl(ws, H_ASH, H_ASL, h * 160 + k, 0.f);
  }
}

// State slabs. mem/bbp per k-chunk: 1 KB, half-index (q'*16+n')*8+j holds
// B[k=f*32+q'*8+j][n']; n'=0..7 hi, n'=8..15 lo(x2048). spk is PACKED to the
// 8 real cols (spike is exact in f16, no lo) -> 512 B/chunk, fully
// overwritten every step (no zero-init). Inactive lanes (c>=8) broadcast-
// read the zero16 block so their S-operand is exactly 0.
struct SLds {
  _Float16 spk[2][4][256];
  _Float16 zero16[8];           // 16 B of zeros, same-address broadcast read
  _Float16 mem[2][4][512];
  _Float16 bbp[2][4][512];
  float red[8][8];
  float red2[8];
};

__global__ __launch_bounds__(512, 2) void snn_main(
    const float* __restrict__ x, const float* __restrict__ y,
    const float* __restrict__ h0m, const float* __restrict__ h0s,
    const float* __restrict__ h0b,
    const float* __restrict__ Wlin, const float* __restrict__ blin,
    const _Float16* __restrict__ W, float* __restrict__ wsout) {
  __shared__ SLds L;

  const int tid  = threadIdx.x;
  const int w    = tid >> 6;      // wave 0..7, owns h-slice [16w, 16w+16)
  const int lane = tid & 63;
  const int c    = lane & 15;     // A-frag m / B-frag n / C col
  const int q    = lane >> 4;
  const int cc   = c & 7;         // batch column within the tile
  const int bbase = blockIdx.x * MTILE;
  const bool act  = (c < 8);
  const bool side = !act;         // side lanes own neurons r=2,3

  // ---- Register-resident A-frag weights (MFMA-only -> AGPR side)
  half8 m1h[5], m1l[5], msh[5], msl[5], ash[5], asl[5];
  half8 wmh[4], wml[4], wbh[4], wbl[4];
  {
    const int hA = w * 16 + c;
#pragma unroll
    for (int f = 0; f < 5; ++f) {
      const int o = hA * 160 + f * 32 + q * 8;
      m1h[f] = *(const half8*)&W[H_M1H + o];
      m1l[f] = *(const half8*)&W[H_M1L + o];
      msh[f] = *(const half8*)&W[H_MSH + o];
      msl[f] = *(const half8*)&W[H_MSL + o];
      ash[f] = *(const half8*)&W[H_ASH + o];
      asl[f] = *(const half8*)&W[H_ASL + o];
    }
#pragma unroll
    for (int f = 0; f < 4; ++f) {
      const int o = hA * 128 + f * 32 + q * 8;
      wmh[f] = *(const half8*)&W[H_WMH + o];
      wml[f] = *(const half8*)&W[H_WML + o];
      wbh[f] = *(const half8*)&W[H_WBH + o];
      wbl[f] = *(const half8*)&W[H_WBL + o];
    }
  }

  if (tid == 0) {   // 16 B zero block for c>=8 broadcast S reads
    *(half8*)&L.zero16[0] = half8{0, 0, 0, 0, 0, 0, 0, 0};
  }

  // ---- Per-lane recurrent state: EVERY lane owns 2 neurons.
  // lane (cc, side, q, w): h = w*16 + q*4 + side*2 + {0,1}, batch bbase+cc.
  float memv[2], spk[2], bb[2];
  {
    const int gi = (bbase + cc) * HID + w * 16 + q * 4 + (side ? 2 : 0);
    float2 tm = *(const float2*)&h0m[gi];
    float2 ts = *(const float2*)&h0s[gi];
    float2 tb = *(const float2*)&h0b[gi];
    memv[0] = tm.x; memv[1] = tm.y;
    spk[0]  = ts.x; spk[1]  = ts.y;
    bb[0]   = tb.x; bb[1]   = tb.y;
  }

  // State value (h = w*16+q*4+side*2+rr) enters GEMM2 as B[k=h][n]:
  // chunk fW = w>>1, granule qp = (w&1)*2 + (q>>1), j = (q&1)*4 + side*2 + rr.
  const int fW  = w >> 1;
  const int qp  = (w & 1) * 2 + (q >> 1);
  const int jo  = (q & 1) * 4 + (side ? 2 : 0);
  const int wiH = (qp * 16 + cc) * 8 + jo;        // mem/bbp hi (n'=cc)
  const int wiL = wiH + 64;                       // mem/bbp lo (n'=cc+8)
  const int wiS = (qp * 8 + cc) * 8 + jo;         // packed spk
  const int ri  = lane * 8;                       // mem/bbp read (identity)
  // spk read: active lanes read their 16 B; side lanes broadcast zero16.
  const _Float16* spkB0 = act ? &L.spk[0][0][(q * 8 + cc) * 8] : L.zero16;
  const _Float16* spkB1 = act ? &L.spk[1][0][(q * 8 + cc) * 8] : L.zero16;
  const int spkStep = act ? 256 : 0;

  {   // initial state into buf 0 (all lanes, 2 values each)
    half2h ps2, mh2, ml2, bh2, bl2;
#pragma unroll
    for (int rr = 0; rr < 2; ++rr) {
      ps2[rr] = (_Float16)spk[rr];
      float v = memv[rr]; _Float16 hi = (_Float16)v;
      mh2[rr] = hi; ml2[rr] = (_Float16)((v - (float)hi) * 2048.0f);
      v = bb[rr]; hi = (_Float16)v;
      bh2[rr] = hi; bl2[rr] = (_Float16)((v - (float)hi) * 2048.0f);
    }
    *(half2h*)&L.spk[0][fW][wiS] = ps2;
    *(half2h*)&L.mem[0][fW][wiH] = mh2; *(half2h*)&L.mem[0][fW][wiL] = ml2;
    *(half2h*)&L.bbp[0][fW][wiH] = bh2; *(half2h*)&L.bbp[0][fW][wiL] = bl2;
  }
  __syncthreads();

  // Per-lane x stream for batch bbase+cc, prefetched one step ahead.
  const float* xb = x + (size_t)(bbase + cc) * 2;
  float2 xv = *(const float2*)xb;   // x at t=0
  const _Float16 e0c = act ? (_Float16)1.0f : (_Float16)0.0f;

#pragma unroll 1
  for (int t = 0; t < S_LEN; ++t) {
    const int p = t & 1, pn = p ^ 1;
    const size_t tn = (t + 1 < S_LEN) ? (size_t)(t + 1) : (size_t)t;
    float2 xnx = *(const float2*)(xb + tn * (size_t)(BATCH * 2));  // prefetch

    // K-extension operand from registers: hi lanes {1, x0h, x1h},
    // lo lanes {0, x0lo, x1lo}; weight rows k>=131 are zero.
    half8 E;
    {
      _Float16 xh0 = (_Float16)xv.x, xh1 = (_Float16)xv.y;
      _Float16 xl0 = (_Float16)((xv.x - (float)xh0) * 2048.0f);
      _Float16 xl1 = (_Float16)((xv.y - (float)xh1) * 2048.0f);
      E = half8{e0c, act ? xh0 : xl0, act ? xh1 : xl1, 0, 0, 0, 0, 0};
    }

    const _Float16* sB = p ? spkB1 : spkB0;

    floatx4 d1 = {0.f,0.f,0.f,0.f}, d2 = {0.f,0.f,0.f,0.f};
    floatx4 m1 = {0.f,0.f,0.f,0.f}, m2 = {0.f,0.f,0.f,0.f};
    floatx4 a1 = {0.f,0.f,0.f,0.f}, a2 = {0.f,0.f,0.f,0.f};

#pragma unroll
    for (int f = 0; f < 4; ++f) {
      half8 S = *(const half8*)&sB[f * spkStep];   // [spk] (0 for c>=8)
      half8 M = *(const half8*)&L.mem[p][f][ri];   // [mh  | ml]
      half8 B = *(const half8*)&L.bbp[p][f][ri];   // [bh  | bl]
      d1 = MFMA(m1h[f], S, d1);
      d2 = MFMA(m1l[f], S, d2);
      m1 = MFMA(msh[f], S, m1);
      m1 = MFMA(wmh[f], M, m1);    // cols0-7: wmh*mh ; cols8-15: wmh*ml
      m2 = MFMA(msl[f], S, m2);
      m2 = MFMA(wml[f], M, m2);    // cols0-7: wml*mh ; cols8-15: junk
      a1 = MFMA(ash[f], S, a1);
      a1 = MFMA(wbh[f], B, a1);
      a2 = MFMA(asl[f], S, a2);
      a2 = MFMA(wbl[f], B, a2);
    }
    {  // K-extension: bias + x coupling, register-built operand
      d1 = MFMA(m1h[4], E, d1);
      d2 = MFMA(m1l[4], E, d2);
      m1 = MFMA(msh[4], E, m1);
      m2 = MFMA(msl[4], E, m2);
      a1 = MFMA(ash[4], E, a1);
      a2 = MFMA(asl[4], E, a2);
    }

    // Fold + redistribute: lane c finishes r=0,1; lane c+8 finishes r=2,3.
    float den[2], preM[2], preA[2];
    fold_pair(d1, d2, side, den);
    fold_pair(m1, m2, side, preM);
    fold_pair(a1, a2, side, preA);

    // ---- Elementwise update: 2 real neurons per lane (64 lanes busy)
    half2h ps2, mh2, ml2, bh2, bl2;
#pragma unroll
    for (int rr = 0; rr < 2; ++rr) {
      float tM = __builtin_amdgcn_rcpf(1.0f + __expf(-preM[rr]));
      float tA = __builtin_amdgcn_rcpf(1.0f + __expf(-preA[rr]));
      bb[rr] = tA * bb[rr] + (1.0f - tA) * spk[rr];
      float Bth = 0.01f + 1.8f * bb[rr];
      memv[rr] = memv[rr] * tM + (1.0f - tM) * den[rr] - Bth * spk[rr];
      spk[rr] = (memv[rr] - Bth) > 0.0f ? 1.0f : 0.0f;
      ps2[rr] = (_Float16)spk[rr];
      float v = memv[rr]; _Float16 hi = (_Float16)v;
      mh2[rr] = hi; ml2[rr] = (_Float16)((v - (float)hi) * 2048.0f);
      v = bb[rr]; hi = (_Float16)v;
      bh2[rr] = hi; bl2[rr] = (_Float16)((v - (float)hi) * 2048.0f);
    }
    *(half2h*)&L.spk[pn][fW][wiS] = ps2;
    *(half2h*)&L.mem[pn][fW][wiH] = mh2; *(half2h*)&L.mem[pn][fW][wiL] = ml2;
    *(half2h*)&L.bbp[pn][fW][wiH] = bh2; *(half2h*)&L.bbp[pn][fW][wiL] = bl2;

    xv = xnx;
    __syncthreads();
  }

  // ---- Readout: out[b] = mem[b,:] @ Wlin + blin; per-block loss partial
  const int h0 = w * 16 + q * 4 + (side ? 2 : 0);
  float part = memv[0] * Wlin[h0] + memv[1] * Wlin[h0 + 1];
  part += __shfl_xor(part, 8);    // sum over side
  part += __shfl_xor(part, 16);   // sum over q
  part += __shfl_xor(part, 32);
  if (lane < 8) L.red[w][c] = part;
  __syncthreads();
  if (tid < 8) {
    float s = 0.0f;
#pragma unroll
    for (int ww = 0; ww < 8; ++ww) s += L.red[ww][tid];
    float out = s + blin[0];
    float d = out - y[bbase + tid];
    L.red2[tid] = d * d;
  }
  __syncthreads();
  if (tid == 0) {
    float s = 0.0f;
#pragma unroll
    for (int m = 0; m < MTILE; ++m) s += L.red2[m];
    wsout[blockIdx.x] = s;
  }
}

__global__ __launch_bounds__(256) void final_reduce(const float* __restrict__ part,
                                                    float* __restrict__ out) {
  __shared__ float sh[256];
  int t = threadIdx.x;
  sh[t] = part[t];
  __syncthreads();
  for (int s = 128; s > 0; s >>= 1) {
    if (t < s) sh[t] += sh[t + s];
    __syncthreads();
  }
  if (t == 0) out[0] = sh[0] * (1.0f / (float)BATCH);
}

extern "C" void kernel_launch(void* const* d_in, const int* in_sizes, int n_in,
                              void* d_out, int out_size, void* d_ws, size_t ws_size,
                              hipStream_t stream) {
  const float* x       = (const float*)d_in[0];
  const float* y       = (const float*)d_in[1];
  const float* h0m     = (const float*)d_in[2];
  const float* h0s     = (const float*)d_in[3];
  const float* h0b     = (const float*)d_in[4];
  const float* W1x     = (const float*)d_in[5];
  const float* b1x     = (const float*)d_in[6];
  const float* WtauM   = (const float*)d_in[7];
  const float* btauM   = (const float*)d_in[8];
  const float* WtauAdp = (const float*)d_in[9];
  const float* btauAdp = (const float*)d_in[10];
  const float* Wlin    = (const float*)d_in[11];
  const float* blin    = (const float*)d_in[12];
  _Float16* wsf16 = (_Float16*)d_ws;
  float* wspart = (float*)d_ws + OFF_PART_F;

  prep<<<128, 192, 0, stream>>>(W1x, b1x, WtauM, btauM, WtauAdp, btauAdp, wsf16);
  snn_main<<<NBLK, 512, 0, stream>>>(x, y, h0m, h0s, h0b, Wlin, blin,
                                     wsf16, wspart);
  final_reduce<<<1, 256, 0, stream>>>(wspart, (float*)d_out);
}

// Round 5
// 1569.406 us; speedup vs baseline: 2.0174x; 1.0837x over previous
//
#include <hip/hip_runtime.h>
#include <math.h>

#define S_LEN 1024
#define BATCH 2048
#define MTILE 8
#define HID   128
#define NBLK  (BATCH / MTILE)   // 256 blocks -> every CU active
#define INV2048 (1.0f / 2048.0f)

// ws layout, offsets in _Float16 elements. Ten [128][128] hi/lo weight
// arrays; the K-extension (bias + x-coupling) lives in a small f32
// coefficient table consumed by the VALU (round-1 numerics, round-4 regs).
#define H_M1H 0
#define H_M1L 16384
#define H_MSH 32768
#define H_MSL 49152
#define H_ASH 65536
#define H_ASL 81920
#define H_WMH 98304      // [128][128] WtauM[:,128:256] hi
#define H_WML 114688
#define H_WBH 131072     // [128][128] WtauAdp[:,128:256] hi
#define H_WBL 147456
// f32 ext-coefficient table: 9 arrays of [128] floats, gate-major:
// idx (gate*3 + col)*128 + h ; gate 0=d,1=M,2=A ; col 0=bias,1=x0,2=x1.
#define F_EXT      81920     // float index (== 163840 halfs)
#define OFF_PART_F 83072     // float index of per-block partials [256]

typedef _Float16 half8 __attribute__((ext_vector_type(8)));
typedef _Float16 half4 __attribute__((ext_vector_type(4)));
typedef _Float16 half2h __attribute__((ext_vector_type(2)));
typedef float floatx4 __attribute__((ext_vector_type(4)));
typedef float floatx2 __attribute__((ext_vector_type(2)));

#define MFMA(a, b, c) __builtin_amdgcn_mfma_f32_16x16x32_f16((a), (b), (c), 0, 0, 0)

__device__ __forceinline__ void put_hl(_Float16* ws, int hiBase, int loBase,
                                       int idx, float v) {
  _Float16 hi = (_Float16)v;
  ws[hiBase + idx] = hi;
  ws[loBase + idx] = (_Float16)((v - (float)hi) * 2048.0f);
}

// DPP row_ror:8 == xor-8 within each 16-lane row (8 = half the 16-ring).
// VALU pipe instead of the over-subscribed LDS pipe.
__device__ __forceinline__ float dpp_xor8(float v) {
  int sw = __builtin_amdgcn_update_dpp(0, __float_as_int(v),
                                       0x128 /*row_ror:8*/, 0xF, 0xF, true);
  return __int_as_float(sw);
}

// u-scheme fold for gates with a cross term (M, A): pre-combine
// u_r = hi_r + lo_r/2048 on the natural side, then one exchange each way.
// Lane c finishes r=0,1; lane c+8 finishes r=2,3.
__device__ __forceinline__ void fold_u(floatx4 g1, floatx4 g2, bool side,
                                       float out[2]) {
  float u0 = g1[0] + g2[0] * INV2048;
  float u1 = g1[1] + g2[1] * INV2048;
  float u2 = g1[2] + g2[2] * INV2048;
  float u3 = g1[3] + g2[3] * INV2048;
  float t0 = dpp_xor8(g1[0]);   // act receives cross_0
  float t1 = dpp_xor8(g1[1]);
  float t2 = dpp_xor8(u2);      // side receives act's u2
  float t3 = dpp_xor8(u3);
  float base0 = side ? t2 : u0, add0 = side ? g1[2] : t0;
  float base1 = side ? t3 : u1, add1 = side ? g1[3] : t1;
  out[0] = base0 + add0 * INV2048;
  out[1] = base1 + add1 * INV2048;
}

// d gate: spk cols 8-15 are exactly 0 -> cross terms vanish on both sides.
__device__ __forceinline__ void fold_d(floatx4 g1, floatx4 g2, bool side,
                                       float out[2]) {
  float u0 = g1[0] + g2[0] * INV2048;
  float u1 = g1[1] + g2[1] * INV2048;
  float u2 = g1[2] + g2[2] * INV2048;
  float u3 = g1[3] + g2[3] * INV2048;
  float t2 = dpp_xor8(u2);
  float t3 = dpp_xor8(u3);
  out[0] = side ? t2 : u0;
  out[1] = side ? t3 : u1;
}

// ---- prep: fold dense->tau coupling into f16 hi/lo fragment arrays, plus
// the f32 ext-coefficient table for the VALU path.
__global__ __launch_bounds__(192) void prep(
    const float* __restrict__ W1x, const float* __restrict__ b1x,
    const float* __restrict__ WtauM, const float* __restrict__ btauM,
    const float* __restrict__ WtauAdp, const float* __restrict__ btauAdp,
    _Float16* __restrict__ ws) {
  const int h = blockIdx.x, k = threadIdx.x;
  if (k >= 131) return;
  if (k < 128) {
    float w1 = W1x[h * 130 + 2 + k];
    float s1 = 0.f, s2 = 0.f;
    for (int d = 0; d < 128; ++d) {
      float wd = W1x[d * 130 + 2 + k];
      s1 += WtauM[h * 256 + d] * wd;
      s2 += WtauAdp[h * 256 + d] * wd;
    }
    put_hl(ws, H_M1H, H_M1L, h * 128 + k, w1);
    put_hl(ws, H_MSH, H_MSL, h * 128 + k, s1);
    put_hl(ws, H_ASH, H_ASL, h * 128 + k, s2);
    put_hl(ws, H_WMH, H_WML, h * 128 + k, WtauM[h * 256 + 128 + k]);
    put_hl(ws, H_WBH, H_WBL, h * 128 + k, WtauAdp[h * 256 + 128 + k]);
  } else {
    const int col = k - 128;   // 0: bias, 1: x0-coef, 2: x1-coef
    float m1v = (col == 0) ? b1x[h] : W1x[h * 130 + (col - 1)];
    float sm = 0.f, sa = 0.f;
    for (int d = 0; d < 128; ++d) {
      float cv = (col == 0) ? b1x[d] : W1x[d * 130 + (col - 1)];
      sm += WtauM[h * 256 + d] * cv;
      sa += WtauAdp[h * 256 + d] * cv;
    }
    if (col == 0) { sm += btauM[h]; sa += btauAdp[h]; }
    float* EXTF = (float*)ws + F_EXT;
    EXTF[(0 * 3 + col) * 128 + h] = m1v;
    EXTF[(1 * 3 + col) * 128 + h] = sm;
    EXTF[(2 * 3 + col) * 128 + h] = sa;
  }
}

// State slabs. mem/bbp per k-chunk: 1 KB, half-index (q'*16+n')*8+j holds
// B[k=f*32+q'*8+j][n']; n'=0..7 hi, n'=8..15 lo(x2048). spk is PACKED to the
// 8 real cols (spike is exact in f16, no lo) -> 512 B/chunk, fully
// overwritten every step. Side lanes broadcast-read zero16 for S.
struct SLds {
  _Float16 spk[2][4][256];
  _Float16 zero16[8];           // 16 B of zeros, same-address broadcast read
  _Float16 mem[2][4][512];
  _Float16 bbp[2][4][512];
  float red[8][8];
  float red2[8];
};

__global__ __launch_bounds__(512, 2) void snn_main(
    const float* __restrict__ x, const float* __restrict__ y,
    const float* __restrict__ h0m, const float* __restrict__ h0s,
    const float* __restrict__ h0b,
    const float* __restrict__ Wlin, const float* __restrict__ blin,
    const _Float16* __restrict__ W, float* __restrict__ wsout) {
  __shared__ SLds L;

  const int tid  = threadIdx.x;
  const int w    = tid >> 6;      // wave 0..7, owns h-slice [16w, 16w+16)
  const int lane = tid & 63;
  const int c    = lane & 15;     // A-frag m / B-frag n / C col
  const int q    = lane >> 4;
  const int cc   = c & 7;         // batch column within the tile
  const int bbase = blockIdx.x * MTILE;
  const bool act  = (c < 8);
  const bool side = !act;         // side lanes own neurons r=2,3

  // ---- Register-resident A-frag weights (MFMA-only -> AGPR side)
  half8 m1h[4], m1l[4], msh[4], msl[4], ash[4], asl[4];
  half8 wmh[4], wml[4], wbh[4], wbl[4];
  {
    const int hA = w * 16 + c;
#pragma unroll
    for (int f = 0; f < 4; ++f) {
      const int o = hA * 128 + f * 32 + q * 8;
      m1h[f] = *(const half8*)&W[H_M1H + o];
      m1l[f] = *(const half8*)&W[H_M1L + o];
      msh[f] = *(const half8*)&W[H_MSH + o];
      msl[f] = *(const half8*)&W[H_MSL + o];
      ash[f] = *(const half8*)&W[H_ASH + o];
      asl[f] = *(const half8*)&W[H_ASL + o];
      wmh[f] = *(const half8*)&W[H_WMH + o];
      wml[f] = *(const half8*)&W[H_WML + o];
      wbh[f] = *(const half8*)&W[H_WBH + o];
      wbl[f] = *(const half8*)&W[H_WBL + o];
    }
  }

  if (tid == 0) {   // 16 B zero block for c>=8 broadcast S reads
    *(half8*)&L.zero16[0] = half8{0, 0, 0, 0, 0, 0, 0, 0};
  }

  // ---- f32 ext coefficients for this lane's 2 neurons (h0i, h0i+1)
  const int h0i = w * 16 + q * 4 + (side ? 2 : 0);
  const float* CF = (const float*)W + F_EXT;
  floatx2 cd0 = *(const floatx2*)&CF[0 * 128 + h0i];
  floatx2 cd1 = *(const floatx2*)&CF[1 * 128 + h0i];
  floatx2 cd2 = *(const floatx2*)&CF[2 * 128 + h0i];
  floatx2 cm0 = *(const floatx2*)&CF[3 * 128 + h0i];
  floatx2 cm1 = *(const floatx2*)&CF[4 * 128 + h0i];
  floatx2 cm2 = *(const floatx2*)&CF[5 * 128 + h0i];
  floatx2 ca0 = *(const floatx2*)&CF[6 * 128 + h0i];
  floatx2 ca1 = *(const floatx2*)&CF[7 * 128 + h0i];
  floatx2 ca2 = *(const floatx2*)&CF[8 * 128 + h0i];

  // ---- Per-lane recurrent state: EVERY lane owns 2 neurons.
  float memv[2], spk[2], bb[2];
  {
    const int gi = (bbase + cc) * HID + h0i;
    float2 tm = *(const float2*)&h0m[gi];
    float2 ts = *(const float2*)&h0s[gi];
    float2 tb = *(const float2*)&h0b[gi];
    memv[0] = tm.x; memv[1] = tm.y;
    spk[0]  = ts.x; spk[1]  = ts.y;
    bb[0]   = tb.x; bb[1]   = tb.y;
  }

  // State value (h = w*16+q*4+side*2+rr) enters GEMM2 as B[k=h][n]:
  // chunk fW = w>>1, granule qp = (w&1)*2 + (q>>1), j = (q&1)*4 + side*2 + rr.
  const int fW  = w >> 1;
  const int qp  = (w & 1) * 2 + (q >> 1);
  const int jo  = (q & 1) * 4 + (side ? 2 : 0);
  const int wiH = (qp * 16 + cc) * 8 + jo;        // mem/bbp hi (n'=cc)
  const int wiL = wiH + 64;                       // mem/bbp lo (n'=cc+8)
  const int wiS = (qp * 8 + cc) * 8 + jo;         // packed spk
  const int ri  = lane * 8;                       // mem/bbp read (identity)
  const _Float16* spkB0 = act ? &L.spk[0][0][(q * 8 + cc) * 8] : L.zero16;
  const _Float16* spkB1 = act ? &L.spk[1][0][(q * 8 + cc) * 8] : L.zero16;
  const int spkStep = act ? 256 : 0;

  {   // initial state into buf 0 (all lanes, 2 values each)
    half2h ps2, mh2, ml2, bh2, bl2;
#pragma unroll
    for (int rr = 0; rr < 2; ++rr) {
      ps2[rr] = (_Float16)spk[rr];
      float v = memv[rr]; _Float16 hi = (_Float16)v;
      mh2[rr] = hi; ml2[rr] = (_Float16)((v - (float)hi) * 2048.0f);
      v = bb[rr]; hi = (_Float16)v;
      bh2[rr] = hi; bl2[rr] = (_Float16)((v - (float)hi) * 2048.0f);
    }
    *(half2h*)&L.spk[0][fW][wiS] = ps2;
    *(half2h*)&L.mem[0][fW][wiH] = mh2; *(half2h*)&L.mem[0][fW][wiL] = ml2;
    *(half2h*)&L.bbp[0][fW][wiH] = bh2; *(half2h*)&L.bbp[0][fW][wiL] = bl2;
  }
  __syncthreads();

  // Per-lane x stream for batch bbase+cc, prefetched one step ahead.
  const float* xb = x + (size_t)(bbase + cc) * 2;
  float2 xv = *(const float2*)xb;   // x at t=0

#pragma unroll 1
  for (int t = 0; t < S_LEN; ++t) {
    const int p = t & 1, pn = p ^ 1;
    const size_t tn = (t + 1 < S_LEN) ? (size_t)(t + 1) : (size_t)t;
    float2 xnx = *(const float2*)(xb + tn * (size_t)(BATCH * 2));  // prefetch

    const _Float16* sB = p ? spkB1 : spkB0;

    floatx4 d1 = {0.f,0.f,0.f,0.f}, d2 = {0.f,0.f,0.f,0.f};
    floatx4 m1 = {0.f,0.f,0.f,0.f}, m2 = {0.f,0.f,0.f,0.f};
    floatx4 a1 = {0.f,0.f,0.f,0.f}, a2 = {0.f,0.f,0.f,0.f};

#pragma unroll
    for (int f = 0; f < 4; ++f) {
      half8 S = *(const half8*)&sB[f * spkStep];   // [spk] (0 for c>=8)
      half8 M = *(const half8*)&L.mem[p][f][ri];   // [mh  | ml]
      half8 B = *(const half8*)&L.bbp[p][f][ri];   // [bh  | bl]
      d1 = MFMA(m1h[f], S, d1);
      d2 = MFMA(m1l[f], S, d2);
      m1 = MFMA(msh[f], S, m1);
      m1 = MFMA(wmh[f], M, m1);    // cols0-7: wmh*mh ; cols8-15: wmh*ml
      m2 = MFMA(msl[f], S, m2);
      m2 = MFMA(wml[f], M, m2);    // cols0-7: wml*mh ; cols8-15: junk
      a1 = MFMA(ash[f], S, a1);
      a1 = MFMA(wbh[f], B, a1);
      a2 = MFMA(asl[f], S, a2);
      a2 = MFMA(wbl[f], B, a2);
    }

    // Fold + redistribute: lane c finishes r=0,1; lane c+8 finishes r=2,3.
    float den[2], preM[2], preA[2];
    fold_d(d1, d2, side, den);
    fold_u(m1, m2, side, preM);
    fold_u(a1, a2, side, preA);

    // ---- Elementwise update: 2 real neurons per lane (64 lanes busy).
    // Ext (bias + x coupling) enters here in exact f32.
    const float xc0 = xv.x, xc1 = xv.y;
    half2h ps2, mh2, ml2, bh2, bl2;
#pragma unroll
    for (int rr = 0; rr < 2; ++rr) {
      float dv = den[rr]  + cd0[rr] + cd1[rr] * xc0 + cd2[rr] * xc1;
      float pM = preM[rr] + cm0[rr] + cm1[rr] * xc0 + cm2[rr] * xc1;
      float pA = preA[rr] + ca0[rr] + ca1[rr] * xc0 + ca2[rr] * xc1;
      float tM = __builtin_amdgcn_rcpf(1.0f + __expf(-pM));
      float tA = __builtin_amdgcn_rcpf(1.0f + __expf(-pA));
      bb[rr] = tA * bb[rr] + (1.0f - tA) * spk[rr];
      float Bth = 0.01f + 1.8f * bb[rr];
      memv[rr] = memv[rr] * tM + (1.0f - tM) * dv - Bth * spk[rr];
      spk[rr] = (memv[rr] - Bth) > 0.0f ? 1.0f : 0.0f;
      ps2[rr] = (_Float16)spk[rr];
      float v = memv[rr]; _Float16 hi = (_Float16)v;
      mh2[rr] = hi; ml2[rr] = (_Float16)((v - (float)hi) * 2048.0f);
      v = bb[rr]; hi = (_Float16)v;
      bh2[rr] = hi; bl2[rr] = (_Float16)((v - (float)hi) * 2048.0f);
    }
    *(half2h*)&L.spk[pn][fW][wiS] = ps2;
    *(half2h*)&L.mem[pn][fW][wiH] = mh2; *(half2h*)&L.mem[pn][fW][wiL] = ml2;
    *(half2h*)&L.bbp[pn][fW][wiH] = bh2; *(half2h*)&L.bbp[pn][fW][wiL] = bl2;

    xv = xnx;
    __syncthreads();
  }

  // ---- Readout: out[b] = mem[b,:] @ Wlin + blin; per-block loss partial
  float part = memv[0] * Wlin[h0i] + memv[1] * Wlin[h0i + 1];
  part += __shfl_xor(part, 8);    // sum over side
  part += __shfl_xor(part, 16);   // sum over q
  part += __shfl_xor(part, 32);
  if (lane < 8) L.red[w][c] = part;
  __syncthreads();
  if (tid < 8) {
    float s = 0.0f;
#pragma unroll
    for (int ww = 0; ww < 8; ++ww) s += L.red[ww][tid];
    float out = s + blin[0];
    float d = out - y[bbase + tid];
    L.red2[tid] = d * d;
  }
  __syncthreads();
  if (tid == 0) {
    float s = 0.0f;
#pragma unroll
    for (int m = 0; m < MTILE; ++m) s += L.red2[m];
    wsout[blockIdx.x] = s;
  }
}

__global__ __launch_bounds__(256) void final_reduce(const float* __restrict__ part,
                                                    float* __restrict__ out) {
  __shared__ float sh[256];
  int t = threadIdx.x;
  sh[t] = part[t];
  __syncthreads();
  for (int s = 128; s > 0; s >>= 1) {
    if (t < s) sh[t] += sh[t + s];
    __syncthreads();
  }
  if (t == 0) out[0] = sh[0] * (1.0f / (float)BATCH);
}

extern "C" void kernel_launch(void* const* d_in, const int* in_sizes, int n_in,
                              void* d_out, int out_size, void* d_ws, size_t ws_size,
                              hipStream_t stream) {
  const float* x       = (const float*)d_in[0];
  const float* y       = (const float*)d_in[1];
  const float* h0m     = (const float*)d_in[2];
  const float* h0s     = (const float*)d_in[3];
  const float* h0b     = (const float*)d_in[4];
  const float* W1x     = (const float*)d_in[5];
  const float* b1x     = (const float*)d_in[6];
  const float* WtauM   = (const float*)d_in[7];
  const float* btauM   = (const float*)d_in[8];
  const float* WtauAdp = (const float*)d_in[9];
  const float* btauAdp = (const float*)d_in[10];
  const float* Wlin    = (const float*)d_in[11];
  const float* blin    = (const float*)d_in[12];
  _Float16* wsf16 = (_Float16*)d_ws;
  float* wspart = (float*)d_ws + OFF_PART_F;

  prep<<<128, 192, 0, stream>>>(W1x, b1x, WtauM, btauM, WtauAdp, btauAdp, wsf16);
  snn_main<<<NBLK, 512, 0, stream>>>(x, y, h0m, h0s, h0b, Wlin, blin,
                                     wsf16, wspart);
  final_reduce<<<1, 256, 0, stream>>>(wspart, (float*)d_out);
}